// Round 2
// baseline (5107.453 us; speedup 1.0000x reference)
//
#include <hip/hip_runtime.h>

#define E_NODES 62
#define TOPK 10
// conv geometry: (5,64) -> c1 5x5 -> (1,60) -> pool -> 30
//                -> c2 1x5 (64ch) -> 26 -> pool -> 13
//                -> c3 1x5 (128ch) -> 9 -> pool -> 4 (pos 8 unused)

// ================= fused conv chain + GP projection =================
// 256 threads / block, 4 images (wave = image).
// LDS floats: img[4][320]@0 | h1[4][32][32]@1280 | h2[4][64][17]@5376
//             wchunk[64][41]@9728 | b2[64]@12352 | b3[128]@12416
//             h3[4][516] aliases @0 (img+h1 dead by conv3)
// total 12544 floats = 50.2 KB -> 3 blocks/CU (12 waves/CU)

__global__ __launch_bounds__(256, 3) void conv_chain_kernel(
    const float* __restrict__ x,
    const float* __restrict__ w1, const float* __restrict__ b1,
    const float* __restrict__ w2, const float* __restrict__ b2,
    const float* __restrict__ w3, const float* __restrict__ b3,
    const float* __restrict__ Wbn1, const float* __restrict__ gc1w,
    float* __restrict__ GP)   // (31744, 96): [0,32)=tanh(Wbn1.h), [32,96)=gc1w.h
{
  __shared__ float sm[12544];
  float* s_img = sm;            // 4*320
  float* s_h1  = sm + 1280;     // 4*32*32 (pitch 32)
  float* s_h3  = sm;            // 4*516 (aliases img+h1, dead by conv3)
  float* s_h2  = sm + 5376;     // 4*64*17 (pitch 17)
  float* s_w   = sm + 9728;     // 64*41 chunk buffer (conv1 w+b fits too)
  float* s_b2  = sm + 12352;    // 64
  float* s_b3  = sm + 12416;    // 128

  const int tid = threadIdx.x;
  const int n0 = blockIdx.x * 4;
  const int im = tid >> 6;
  const int lane = tid & 63;

  for (int i = tid; i < 1280; i += 256) s_img[i] = x[(size_t)n0 * 320 + i];
  for (int i = tid; i < 832; i += 256) s_w[i] = (i < 800) ? w1[i] : b1[i - 800];
  for (int i = tid; i < 192; i += 256) {
    if (i < 64) s_b2[i] = b2[i]; else s_b3[i - 64] = b3[i - 64];
  }
  __syncthreads();

  // ---- conv1 + relu + pool. lane = (half, tp): tp = pooled pos, conflict-free writes
  {
    const int tp = lane & 31;        // 0..29 used
    const int half = lane >> 5;      // output-channel half
    if (tp < 30) {
      const float* ib = s_img + im * 320;
      const int t0 = 2 * tp;
      float r[5][6];
#pragma unroll
      for (int kr = 0; kr < 5; ++kr)
#pragma unroll
        for (int c = 0; c < 6; ++c) r[kr][c] = ib[kr * 64 + t0 + c];
#pragma unroll
      for (int oi = 0; oi < 16; ++oi) {
        const int o = half * 16 + oi;
        const float* w = s_w + o * 25;        // broadcast reads
        const float bia = s_w[800 + o];
        float s0 = bia, s1 = bia;
#pragma unroll
        for (int kr = 0; kr < 5; ++kr) {
#pragma unroll
          for (int k = 0; k < 5; ++k) {
            const float wv = w[kr * 5 + k];
            s0 += r[kr][k] * wv;
            s1 += r[kr][k + 1] * wv;
          }
        }
        s_h1[im * 1024 + o * 32 + tp] = fmaxf(fmaxf(s0, s1), 0.f);  // stride-1 lanes: no conflict
      }
    }
  }

  // ---- conv2 + relu + pool: thread = (im, o); weights chunked 8 ci at a time
  {
    const int o = lane;
    float acc0[13], acc1[13];
    const float bia = s_b2[o];
#pragma unroll
    for (int t = 0; t < 13; ++t) { acc0[t] = bia; acc1[t] = bia; }
#pragma unroll 1
    for (int c = 0; c < 4; ++c) {
      __syncthreads();
      for (int i = tid; i < 2560; i += 256) {
        const int oo = i / 40, rr = i - oo * 40;
        s_w[oo * 41 + rr] = w2[oo * 160 + c * 40 + rr];
      }
      __syncthreads();
#pragma unroll
      for (int cl = 0; cl < 8; ++cl) {
        const int ci = c * 8 + cl;
        const float* hr = s_h1 + im * 1024 + ci * 32;   // wave-broadcast
        float r[30];
#pragma unroll
        for (int q = 0; q < 7; ++q) {
          const float4 v = *(const float4*)(hr + q * 4);
          r[q * 4] = v.x; r[q * 4 + 1] = v.y; r[q * 4 + 2] = v.z; r[q * 4 + 3] = v.w;
        }
        { const float2 v = *(const float2*)(hr + 28); r[28] = v.x; r[29] = v.y; }
        const float* w = s_w + o * 41 + cl * 5;         // stride 41: conflict-free
        const float w0 = w[0], w1_ = w[1], w2_ = w[2], w3_ = w[3], w4_ = w[4];
#pragma unroll
        for (int t = 0; t < 13; ++t) {
          const int t0 = 2 * t;
          acc0[t] += r[t0] * w0 + r[t0 + 1] * w1_ + r[t0 + 2] * w2_ + r[t0 + 3] * w3_ + r[t0 + 4] * w4_;
          acc1[t] += r[t0 + 1] * w0 + r[t0 + 2] * w1_ + r[t0 + 3] * w2_ + r[t0 + 4] * w3_ + r[t0 + 5] * w4_;
        }
      }
    }
    __syncthreads();
#pragma unroll
    for (int t = 0; t < 13; ++t)
      s_h2[im * 1088 + o * 17 + t] = fmaxf(fmaxf(acc0[t], acc1[t]), 0.f);  // odd pitch: free
  }

  // ---- conv3 + relu + pool -> s_h3 (aliases img/h1)
  {
    const int oc = lane;
#pragma unroll 1
    for (int ch = 0; ch < 2; ++ch) {
      float acc[8];
      const float bia = s_b3[ch * 64 + oc];
#pragma unroll
      for (int t = 0; t < 8; ++t) acc[t] = bia;
#pragma unroll 1
      for (int c = 0; c < 8; ++c) {
        __syncthreads();
        for (int i = tid; i < 2560; i += 256) {
          const int oo = i / 40, rr = i - oo * 40;
          s_w[oo * 41 + rr] = w3[(ch * 64 + oo) * 320 + c * 40 + rr];
        }
        __syncthreads();
#pragma unroll
        for (int cl = 0; cl < 8; ++cl) {
          const int ci = c * 8 + cl;
          const float* hr = s_h2 + im * 1088 + ci * 17;  // wave-broadcast scalars
          float r[12];
#pragma unroll
          for (int t = 0; t < 12; ++t) r[t] = hr[t];
          const float* w = s_w + oc * 41 + cl * 5;
          const float w0 = w[0], w1_ = w[1], w2_ = w[2], w3_ = w[3], w4_ = w[4];
#pragma unroll
          for (int t = 0; t < 8; ++t)
            acc[t] += r[t] * w0 + r[t + 1] * w1_ + r[t + 2] * w2_ + r[t + 3] * w3_ + r[t + 4] * w4_;
        }
      }
#pragma unroll
      for (int j = 0; j < 4; ++j)
        s_h3[im * 516 + (ch * 64 + oc) * 4 + j] = fmaxf(fmaxf(acc[2 * j], acc[2 * j + 1]), 0.f);
    }
  }
  __syncthreads();

  // ---- GP tail: p = gc1w.h (64), g = tanh(Wbn1.h) (32). h broadcast from LDS.
  {
    const float* hb = s_h3 + im * 516;
    float* gpo = GP + (size_t)(n0 + im) * 96;
    {
      const float* wrow = gc1w + (size_t)lane * 512;
      float acc = 0.f;
#pragma unroll 4
      for (int j = 0; j < 128; ++j) {
        const float4 wv = *(const float4*)(wrow + 4 * j);
        const float4 hv = *(const float4*)(hb + 4 * j);
        acc += wv.x * hv.x + wv.y * hv.y + wv.z * hv.z + wv.w * hv.w;
      }
      gpo[32 + lane] = acc;
    }
    {
      const int q = lane & 31;
      const float* wrow = Wbn1 + (size_t)q * 512;
      float acc = 0.f;
#pragma unroll 4
      for (int j = 0; j < 128; ++j) {
        const float4 wv = *(const float4*)(wrow + 4 * j);
        const float4 hv = *(const float4*)(hb + 4 * j);
        acc += wv.x * hv.x + wv.y * hv.y + wv.z * hv.z + wv.w * hv.w;
      }
      if (lane < 32) gpo[q] = 1.f - 2.f / (__expf(2.f * acc) + 1.f);
    }
  }
}

// ================= SOGC layer 1 (consumes GP) =================
__global__ __launch_bounds__(256) void sogc1_kernel(
    const float* __restrict__ GP, const float* __restrict__ gcb,
    float* __restrict__ Hout)
{
  __shared__ float sG[62 * 33];
  __shared__ float sP[62 * 64];
  __shared__ float stv[620];
  __shared__ int   sti[620];
  const int b = blockIdx.x, tid = threadIdx.x;
  const int lane = tid & 63, wave = tid >> 6;

  const float* gp = GP + (size_t)b * 62 * 96;
  for (int i = tid; i < 62 * 96; i += 256) {
    const int e = i / 96, q = i - e * 96;
    const float v = gp[i];
    if (q < 32) sG[e * 33 + q] = v; else sP[e * 64 + (q - 32)] = v;
  }
  __syncthreads();

  // scores -> softmax -> top-10
  for (int e = wave; e < E_NODES; e += 4) {
    float sc = -1e30f;
    if (lane < E_NODES) {
      float s = 0.f;
#pragma unroll
      for (int k = 0; k < 32; ++k) s += sG[e * 33 + k] * sG[lane * 33 + k];
      sc = s;
    }
    float mx = sc;
#pragma unroll
    for (int off = 32; off; off >>= 1) mx = fmaxf(mx, __shfl_xor(mx, off));
    float p = (lane < E_NODES) ? __expf(sc - mx) : 0.f;
    float sum = p;
#pragma unroll
    for (int off = 32; off; off >>= 1) sum += __shfl_xor(sum, off);
    p = p / sum;
    float v = (lane < E_NODES) ? p : -1.f;
#pragma unroll 1
    for (int it = 0; it < TOPK; ++it) {
      float bv = v; int bi = lane;
#pragma unroll
      for (int off = 32; off; off >>= 1) {
        const float ov = __shfl_xor(bv, off);
        const int   oi = __shfl_xor(bi, off);
        if (ov > bv || (ov == bv && oi < bi)) { bv = ov; bi = oi; }
      }
      if (lane == 0) { stv[e * 10 + it] = bv; sti[e * 10 + it] = bi; }
      if (lane == bi) v = -1.f;
    }
  }
  __syncthreads();

  for (int e = wave; e < E_NODES; e += 4) {
    float acc = gcb[lane];
#pragma unroll
    for (int j = 0; j < TOPK; ++j)
      acc += stv[e * 10 + j] * sP[sti[e * 10 + j] * 64 + lane];
    Hout[((size_t)b * E_NODES + e) * 64 + lane] = fmaxf(acc, 0.f);
  }
}

// ================= SOGC layers 2/3 (DIN=64), cls fused into layer 3 =================
// LDS: sH[62*65] | sWt[64*97] (cols 0..63 = gcw^T, 64..95 = Wbn^T) | sG | sP | topk
template <bool CLS>
__global__ __launch_bounds__(256) void sogc64_kernel(
    const float* __restrict__ Hin, const float* __restrict__ Wbn,
    const float* __restrict__ gcw, const float* __restrict__ gcb,
    const float* __restrict__ cw, const float* __restrict__ cb,
    float* __restrict__ outbuf)   // Hout (b,62,64) or logits (b,4)
{
  extern __shared__ float sm[];
  float* sH  = sm;                 // 62*65 = 4030
  float* sWt = sm + 4030;          // 64*97 = 6208
  float* sG  = sm + 10238;         // 62*33 = 2046
  float* sP  = sm + 12284;         // 62*64 = 3968
  float* stv = sm + 16252;         // 620
  int*   sti = (int*)(sm + 16872); // 620
  float* sred = sm + 17492;        // 16

  const int b = blockIdx.x, tid = threadIdx.x;
  const int lane = tid & 63, wave = tid >> 6;

  const float* Hb = Hin + (size_t)b * 62 * 64;
  for (int i = tid; i < 62 * 64; i += 256)
    sH[(i >> 6) * 65 + (i & 63)] = Hb[i];
  for (int i = tid; i < 64 * 64; i += 256)        // gcw (o,d) -> sWt[d][o]
    sWt[(i & 63) * 97 + (i >> 6)] = gcw[i];
  for (int i = tid; i < 32 * 64; i += 256)        // Wbn (k,d) -> sWt[d][64+k]
    sWt[(i & 63) * 97 + 64 + (i >> 6)] = Wbn[i];
  __syncthreads();

  // G and P: lane = output column, H row broadcast
  for (int e = wave; e < E_NODES; e += 4) {
    const float* hrow = sH + e * 65;
    const float* wp = sWt + lane;
    const float* wg = sWt + 64 + (lane & 31);
    float accp = 0.f, accg = 0.f;
#pragma unroll 8
    for (int d = 0; d < 64; ++d) {
      const float h = hrow[d];
      accp += h * wp[d * 97];
      accg += h * wg[d * 97];
    }
    sP[e * 64 + lane] = accp;
    if (lane < 32) sG[e * 33 + lane] = 1.f - 2.f / (__expf(2.f * accg) + 1.f);
  }
  __syncthreads();

  for (int e = wave; e < E_NODES; e += 4) {
    float sc = -1e30f;
    if (lane < E_NODES) {
      float s = 0.f;
#pragma unroll
      for (int k = 0; k < 32; ++k) s += sG[e * 33 + k] * sG[lane * 33 + k];
      sc = s;
    }
    float mx = sc;
#pragma unroll
    for (int off = 32; off; off >>= 1) mx = fmaxf(mx, __shfl_xor(mx, off));
    float p = (lane < E_NODES) ? __expf(sc - mx) : 0.f;
    float sum = p;
#pragma unroll
    for (int off = 32; off; off >>= 1) sum += __shfl_xor(sum, off);
    p = p / sum;
    float v = (lane < E_NODES) ? p : -1.f;
#pragma unroll 1
    for (int it = 0; it < TOPK; ++it) {
      float bv = v; int bi = lane;
#pragma unroll
      for (int off = 32; off; off >>= 1) {
        const float ov = __shfl_xor(bv, off);
        const int   oi = __shfl_xor(bi, off);
        if (ov > bv || (ov == bv && oi < bi)) { bv = ov; bi = oi; }
      }
      if (lane == 0) { stv[e * 10 + it] = bv; sti[e * 10 + it] = bi; }
      if (lane == bi) v = -1.f;
    }
  }
  __syncthreads();

  float accn[4] = {0.f, 0.f, 0.f, 0.f};
  for (int e = wave; e < E_NODES; e += 4) {
    float acc = gcb[lane];
#pragma unroll
    for (int j = 0; j < TOPK; ++j)
      acc += stv[e * 10 + j] * sP[sti[e * 10 + j] * 64 + lane];
    acc = fmaxf(acc, 0.f);
    if (CLS) {
#pragma unroll
      for (int n = 0; n < 4; ++n)
        accn[n] += acc * cw[n * 3968 + e * 64 + lane];
    } else {
      outbuf[((size_t)b * E_NODES + e) * 64 + lane] = acc;
    }
  }
  if (CLS) {
#pragma unroll
    for (int n = 0; n < 4; ++n) {
      float s = accn[n];
#pragma unroll
      for (int off = 32; off; off >>= 1) s += __shfl_xor(s, off);
      if (lane == 0) sred[wave * 4 + n] = s;
    }
    __syncthreads();
    if (tid < 4)
      outbuf[b * 4 + tid] = cb[tid] + sred[tid] + sred[4 + tid] + sred[8 + tid] + sred[12 + tid];
  }
}

// ================= launch =================
extern "C" void kernel_launch(void* const* d_in, const int* in_sizes, int n_in,
                              void* d_out, int out_size, void* d_ws, size_t ws_size,
                              hipStream_t stream) {
  const float* x    = (const float*)d_in[0];
  const float* c1w  = (const float*)d_in[1];
  const float* c1b  = (const float*)d_in[2];
  const float* c2w  = (const float*)d_in[3];
  const float* c2b  = (const float*)d_in[4];
  const float* c3w  = (const float*)d_in[5];
  const float* c3b  = (const float*)d_in[6];
  const float* Wbn1 = (const float*)d_in[7];
  const float* gc1w = (const float*)d_in[8];
  const float* gc1b = (const float*)d_in[9];
  const float* Wbn2 = (const float*)d_in[10];
  const float* gc2w = (const float*)d_in[11];
  const float* gc2b = (const float*)d_in[12];
  const float* Wbn3 = (const float*)d_in[13];
  const float* gc3w = (const float*)d_in[14];
  const float* gc3b = (const float*)d_in[15];
  const float* clsw = (const float*)d_in[16];
  const float* clsb = (const float*)d_in[17];
  float* out = (float*)d_out;

  float* wsf = (float*)d_ws;
  float* GP  = wsf;                        // 31744*96 = 3,047,424 floats
  float* Hs1 = wsf + (size_t)3047424;      // 512*62*64 = 2,031,616
  float* Hs2 = Hs1 + (size_t)2031616;      // total ~28.5 MB

  const int SOGC64_BYTES = 17508 * 4;      // 70,032 B dynamic LDS

  (void)hipFuncSetAttribute((const void*)sogc64_kernel<false>,
                            hipFuncAttributeMaxDynamicSharedMemorySize, SOGC64_BYTES);
  (void)hipFuncSetAttribute((const void*)sogc64_kernel<true>,
                            hipFuncAttributeMaxDynamicSharedMemorySize, SOGC64_BYTES);

  conv_chain_kernel<<<7936, 256, 0, stream>>>(x, c1w, c1b, c2w, c2b, c3w, c3b,
                                              Wbn1, gc1w, GP);
  sogc1_kernel<<<512, 256, 0, stream>>>(GP, gc1b, Hs1);
  sogc64_kernel<false><<<512, 256, SOGC64_BYTES, stream>>>(
      Hs1, Wbn2, gc2w, gc2b, nullptr, nullptr, Hs2);
  sogc64_kernel<true><<<512, 256, SOGC64_BYTES, stream>>>(
      Hs2, Wbn3, gc3w, gc3b, clsw, clsb, out);
}

// Round 3
// 2489.982 us; speedup vs baseline: 2.0512x; 2.0512x over previous
//
#include <hip/hip_runtime.h>

#define E_NODES 62
#define TOPK 10
// conv geometry: (5,64) -> c1 5x5 -> (1,60) -> pool -> 30
//                -> c2 1x5 (64ch) -> 26 -> pool -> 13
//                -> c3 1x5 (128ch) -> 9 -> pool -> 4 (pos 8 unused)

// ================= fused conv chain =================
// 256 threads / block, 4 images (wave = image). Writes H3 (31744,512).
// LDS floats: img[4][320]@0 | h1[4][32][32]@1280 | h2[4][64][20]@5376
//             wchunk[64][41]@10496 | b2[64]@13120 | b3[128]@13184
// total 13312 floats = 52 KB -> 3 blocks/CU

__global__ __launch_bounds__(256) void conv_chain_kernel(
    const float* __restrict__ x,
    const float* __restrict__ w1, const float* __restrict__ b1,
    const float* __restrict__ w2, const float* __restrict__ b2,
    const float* __restrict__ w3, const float* __restrict__ b3,
    float* __restrict__ H3)
{
  __shared__ float sm[13312];
  float* s_img = sm;            // 4*320
  float* s_h1  = sm + 1280;     // 4*32*32 (pitch 32; conflict-free via lane=tp writes)
  float* s_h2  = sm + 5376;     // 4*64*20 (pitch 20; aligned float4 reads)
  float* s_w   = sm + 10496;    // 64*41 = 2624 chunk buffer (w1's 832 fits too)
  float* s_b2  = sm + 13120;    // 64
  float* s_b3  = sm + 13184;    // 128

  const int tid = threadIdx.x;
  const int n0 = blockIdx.x * 4;
  const int im = tid >> 6;
  const int lane = tid & 63;

  for (int i = tid; i < 1280; i += 256) s_img[i] = x[(size_t)n0 * 320 + i];
  for (int i = tid; i < 832; i += 256) s_w[i] = (i < 800) ? w1[i] : b1[i - 800];
  for (int i = tid; i < 192; i += 256) {
    if (i < 64) s_b2[i] = b2[i]; else s_b3[i - 64] = b3[i - 64];
  }
  __syncthreads();

  // ---- conv1 + relu + pool. lane = (half, tp): stride-1 writes (no conflict)
  {
    const int tp = lane & 31;        // pooled position, 0..29 used
    const int half = lane >> 5;      // output-channel half
    if (tp < 30) {
      const float* ib = s_img + im * 320;
      const int t0 = 2 * tp;
      float r[5][6];
#pragma unroll
      for (int kr = 0; kr < 5; ++kr)
#pragma unroll
        for (int c = 0; c < 6; ++c) r[kr][c] = ib[kr * 64 + t0 + c];
#pragma unroll
      for (int oi = 0; oi < 16; ++oi) {
        const int o = half * 16 + oi;
        const float* w = s_w + o * 25;        // 2-address broadcast reads
        const float bia = s_w[800 + o];
        float s0 = bia, s1 = bia;
#pragma unroll
        for (int kr = 0; kr < 5; ++kr) {
#pragma unroll
          for (int k = 0; k < 5; ++k) {
            const float wv = w[kr * 5 + k];
            s0 += r[kr][k] * wv;
            s1 += r[kr][k + 1] * wv;
          }
        }
        s_h1[im * 1024 + o * 32 + tp] = fmaxf(fmaxf(s0, s1), 0.f);
      }
    }
  }

  // ---- conv2 + relu + pool: thread = (im, o); weights chunked 8 ci
  {
    const int o = lane;
    float acc0[13], acc1[13];
    const float bia = s_b2[o];
#pragma unroll
    for (int t = 0; t < 13; ++t) { acc0[t] = bia; acc1[t] = bia; }
#pragma unroll 1
    for (int c = 0; c < 4; ++c) {
      __syncthreads();
      for (int i = tid; i < 2560; i += 256) {
        const int oo = i / 40, rr = i - oo * 40;
        s_w[oo * 41 + rr] = w2[oo * 160 + c * 40 + rr];
      }
      __syncthreads();
#pragma unroll
      for (int cl = 0; cl < 8; ++cl) {
        const int ci = c * 8 + cl;
        const float* hr = s_h1 + im * 1024 + ci * 32;   // wave-broadcast, 16B-aligned
        float r[30];
#pragma unroll
        for (int q = 0; q < 7; ++q) {
          const float4 v = *(const float4*)(hr + q * 4);
          r[q * 4] = v.x; r[q * 4 + 1] = v.y; r[q * 4 + 2] = v.z; r[q * 4 + 3] = v.w;
        }
        { const float2 v = *(const float2*)(hr + 28); r[28] = v.x; r[29] = v.y; }
        const float* w = s_w + o * 41 + cl * 5;         // 41 coprime 32: conflict-free
        const float w0 = w[0], w1_ = w[1], w2_ = w[2], w3_ = w[3], w4_ = w[4];
#pragma unroll
        for (int t = 0; t < 13; ++t) {
          const int t0 = 2 * t;
          acc0[t] += r[t0] * w0 + r[t0 + 1] * w1_ + r[t0 + 2] * w2_ + r[t0 + 3] * w3_ + r[t0 + 4] * w4_;
          acc1[t] += r[t0 + 1] * w0 + r[t0 + 2] * w1_ + r[t0 + 3] * w2_ + r[t0 + 4] * w3_ + r[t0 + 5] * w4_;
        }
      }
    }
    __syncthreads();
#pragma unroll
    for (int t = 0; t < 13; ++t)
      s_h2[im * 1280 + o * 20 + t] = fmaxf(fmaxf(acc0[t], acc1[t]), 0.f);  // 8-way on 13 writes: minor
  }

  // ---- conv3 + relu + pool -> H3 global (coalesced float4)
  {
    const int oc = lane;
#pragma unroll 1
    for (int ch = 0; ch < 2; ++ch) {
      float acc[8];
      const float bia = s_b3[ch * 64 + oc];
#pragma unroll
      for (int t = 0; t < 8; ++t) acc[t] = bia;
#pragma unroll 1
      for (int c = 0; c < 8; ++c) {
        __syncthreads();
        for (int i = tid; i < 2560; i += 256) {
          const int oo = i / 40, rr = i - oo * 40;
          s_w[oo * 41 + rr] = w3[(ch * 64 + oo) * 320 + c * 40 + rr];
        }
        __syncthreads();
#pragma unroll
        for (int cl = 0; cl < 8; ++cl) {
          const int ci = c * 8 + cl;
          const float* hr = s_h2 + im * 1280 + ci * 20;  // wave-broadcast, aligned
          float r[12];
#pragma unroll
          for (int q = 0; q < 3; ++q) {
            const float4 v = *(const float4*)(hr + q * 4);
            r[q * 4] = v.x; r[q * 4 + 1] = v.y; r[q * 4 + 2] = v.z; r[q * 4 + 3] = v.w;
          }
          const float* w = s_w + oc * 41 + cl * 5;
          const float w0 = w[0], w1_ = w[1], w2_ = w[2], w3_ = w[3], w4_ = w[4];
#pragma unroll
          for (int t = 0; t < 8; ++t)
            acc[t] += r[t] * w0 + r[t + 1] * w1_ + r[t + 2] * w2_ + r[t + 3] * w3_ + r[t + 4] * w4_;
        }
      }
      float4 ov;
      ov.x = fmaxf(fmaxf(acc[0], acc[1]), 0.f);
      ov.y = fmaxf(fmaxf(acc[2], acc[3]), 0.f);
      ov.z = fmaxf(fmaxf(acc[4], acc[5]), 0.f);
      ov.w = fmaxf(fmaxf(acc[6], acc[7]), 0.f);
      *(float4*)(H3 + (size_t)(n0 + im) * 512 + (size_t)(ch * 64 + oc) * 4) = ov;
    }
  }
}

// ================= GP projection: GP[n][0:32)=tanh(Wbn1.h), [32:96)=gc1w.h ==========
// block = 32 images, 256 threads; thread = (im=tid>>3, oq=tid&7) -> 12 outputs each.
__global__ __launch_bounds__(256) void gp_kernel(
    const float* __restrict__ H3, const float* __restrict__ Wbn1,
    const float* __restrict__ gc1w, float* __restrict__ GP)
{
  __shared__ float sH[32 * 65];   // pitch 65
  __shared__ float sW[96 * 65];
  const int tid = threadIdx.x;
  const int n0 = blockIdx.x * 32;
  const int im = tid >> 3;
  const int oq = tid & 7;

  float acc[12];
#pragma unroll
  for (int j = 0; j < 12; ++j) acc[j] = 0.f;

#pragma unroll 1
  for (int c8 = 0; c8 < 8; ++c8) {
    const int d0 = c8 * 64;
    __syncthreads();
    for (int i = tid; i < 2048; i += 256) {
      const int r = i >> 6, cc = i & 63;
      sH[r * 65 + cc] = H3[(size_t)(n0 + r) * 512 + d0 + cc];   // coalesced
    }
    for (int i = tid; i < 6144; i += 256) {
      const int o = i >> 6, cc = i & 63;
      sW[o * 65 + cc] = (o < 32) ? Wbn1[o * 512 + d0 + cc]
                                 : gc1w[(o - 32) * 512 + d0 + cc];
    }
    __syncthreads();
#pragma unroll 4
    for (int d = 0; d < 64; ++d) {
      const float h = sH[im * 65 + d];     // 8 addrs/wave: conflict-free
#pragma unroll
      for (int j = 0; j < 12; ++j)
        acc[j] += h * sW[(oq * 12 + j) * 65 + d];   // 8 distinct banks
    }
  }
  float* gpo = GP + (size_t)(n0 + im) * 96;
#pragma unroll
  for (int j = 0; j < 12; ++j) {
    const int o = oq * 12 + j;
    gpo[o] = (o < 32) ? (1.f - 2.f / (__expf(2.f * acc[j]) + 1.f)) : acc[j];
  }
}

// ================= SOGC layer 1 (consumes GP) =================
__global__ __launch_bounds__(256) void sogc1_kernel(
    const float* __restrict__ GP, const float* __restrict__ gcb,
    float* __restrict__ Hout)
{
  __shared__ float sG[62 * 33];
  __shared__ float sP[62 * 64];
  __shared__ float stv[620];
  __shared__ int   sti[620];
  const int b = blockIdx.x, tid = threadIdx.x;
  const int lane = tid & 63, wave = tid >> 6;

  const float* gp = GP + (size_t)b * 62 * 96;
  for (int i = tid; i < 62 * 96; i += 256) {
    const int e = i / 96, q = i - e * 96;
    const float v = gp[i];
    if (q < 32) sG[e * 33 + q] = v; else sP[e * 64 + (q - 32)] = v;
  }
  __syncthreads();

  for (int e = wave; e < E_NODES; e += 4) {
    float sc = -1e30f;
    if (lane < E_NODES) {
      float s = 0.f;
#pragma unroll
      for (int k = 0; k < 32; ++k) s += sG[e * 33 + k] * sG[lane * 33 + k];
      sc = s;
    }
    float mx = sc;
#pragma unroll
    for (int off = 32; off; off >>= 1) mx = fmaxf(mx, __shfl_xor(mx, off));
    float p = (lane < E_NODES) ? __expf(sc - mx) : 0.f;
    float sum = p;
#pragma unroll
    for (int off = 32; off; off >>= 1) sum += __shfl_xor(sum, off);
    p = p / sum;
    float v = (lane < E_NODES) ? p : -1.f;
#pragma unroll 1
    for (int it = 0; it < TOPK; ++it) {
      float bv = v; int bi = lane;
#pragma unroll
      for (int off = 32; off; off >>= 1) {
        const float ov = __shfl_xor(bv, off);
        const int   oi = __shfl_xor(bi, off);
        if (ov > bv || (ov == bv && oi < bi)) { bv = ov; bi = oi; }  // lax.top_k tie-break
      }
      if (lane == 0) { stv[e * 10 + it] = bv; sti[e * 10 + it] = bi; }
      if (lane == bi) v = -1.f;
    }
  }
  __syncthreads();

  for (int e = wave; e < E_NODES; e += 4) {
    float acc = gcb[lane];
#pragma unroll
    for (int j = 0; j < TOPK; ++j)
      acc += stv[e * 10 + j] * sP[sti[e * 10 + j] * 64 + lane];
    Hout[((size_t)b * E_NODES + e) * 64 + lane] = fmaxf(acc, 0.f);
  }
}

// ================= SOGC layers 2/3 (DIN=64), cls fused into layer 3 =================
template <bool CLS>
__global__ __launch_bounds__(256) void sogc64_kernel(
    const float* __restrict__ Hin, const float* __restrict__ Wbn,
    const float* __restrict__ gcw, const float* __restrict__ gcb,
    const float* __restrict__ cw, const float* __restrict__ cb,
    float* __restrict__ outbuf)   // Hout (b,62,64) or logits (b,4)
{
  extern __shared__ float sm[];
  float* sH  = sm;                 // 62*65 = 4030
  float* sWt = sm + 4030;          // 64*97 = 6208
  float* sG  = sm + 10238;         // 62*33 = 2046
  float* sP  = sm + 12284;         // 62*64 = 3968
  float* stv = sm + 16252;         // 620
  int*   sti = (int*)(sm + 16872); // 620
  float* sred = sm + 17492;        // 16

  const int b = blockIdx.x, tid = threadIdx.x;
  const int lane = tid & 63, wave = tid >> 6;

  const float* Hb = Hin + (size_t)b * 62 * 64;
  for (int i = tid; i < 62 * 64; i += 256)
    sH[(i >> 6) * 65 + (i & 63)] = Hb[i];
  for (int i = tid; i < 64 * 64; i += 256)        // gcw (o,d) -> sWt[d][o]
    sWt[(i & 63) * 97 + (i >> 6)] = gcw[i];
  for (int i = tid; i < 32 * 64; i += 256)        // Wbn (k,d) -> sWt[d][64+k]
    sWt[(i & 63) * 97 + 64 + (i >> 6)] = Wbn[i];
  __syncthreads();

  for (int e = wave; e < E_NODES; e += 4) {
    const float* hrow = sH + e * 65;
    const float* wp = sWt + lane;
    const float* wg = sWt + 64 + (lane & 31);
    float accp = 0.f, accg = 0.f;
#pragma unroll 8
    for (int d = 0; d < 64; ++d) {
      const float h = hrow[d];
      accp += h * wp[d * 97];
      accg += h * wg[d * 97];
    }
    sP[e * 64 + lane] = accp;
    if (lane < 32) sG[e * 33 + lane] = 1.f - 2.f / (__expf(2.f * accg) + 1.f);
  }
  __syncthreads();

  for (int e = wave; e < E_NODES; e += 4) {
    float sc = -1e30f;
    if (lane < E_NODES) {
      float s = 0.f;
#pragma unroll
      for (int k = 0; k < 32; ++k) s += sG[e * 33 + k] * sG[lane * 33 + k];
      sc = s;
    }
    float mx = sc;
#pragma unroll
    for (int off = 32; off; off >>= 1) mx = fmaxf(mx, __shfl_xor(mx, off));
    float p = (lane < E_NODES) ? __expf(sc - mx) : 0.f;
    float sum = p;
#pragma unroll
    for (int off = 32; off; off >>= 1) sum += __shfl_xor(sum, off);
    p = p / sum;
    float v = (lane < E_NODES) ? p : -1.f;
#pragma unroll 1
    for (int it = 0; it < TOPK; ++it) {
      float bv = v; int bi = lane;
#pragma unroll
      for (int off = 32; off; off >>= 1) {
        const float ov = __shfl_xor(bv, off);
        const int   oi = __shfl_xor(bi, off);
        if (ov > bv || (ov == bv && oi < bi)) { bv = ov; bi = oi; }
      }
      if (lane == 0) { stv[e * 10 + it] = bv; sti[e * 10 + it] = bi; }
      if (lane == bi) v = -1.f;
    }
  }
  __syncthreads();

  float accn[4] = {0.f, 0.f, 0.f, 0.f};
  for (int e = wave; e < E_NODES; e += 4) {
    float acc = gcb[lane];
#pragma unroll
    for (int j = 0; j < TOPK; ++j)
      acc += stv[e * 10 + j] * sP[sti[e * 10 + j] * 64 + lane];
    acc = fmaxf(acc, 0.f);
    if (CLS) {
#pragma unroll
      for (int n = 0; n < 4; ++n)
        accn[n] += acc * cw[n * 3968 + e * 64 + lane];
    } else {
      outbuf[((size_t)b * E_NODES + e) * 64 + lane] = acc;
    }
  }
  if (CLS) {
#pragma unroll
    for (int n = 0; n < 4; ++n) {
      float s = accn[n];
#pragma unroll
      for (int off = 32; off; off >>= 1) s += __shfl_xor(s, off);
      if (lane == 0) sred[wave * 4 + n] = s;
    }
    __syncthreads();
    if (tid < 4)
      outbuf[b * 4 + tid] = cb[tid] + sred[tid] + sred[4 + tid] + sred[8 + tid] + sred[12 + tid];
  }
}

// ================= launch =================
extern "C" void kernel_launch(void* const* d_in, const int* in_sizes, int n_in,
                              void* d_out, int out_size, void* d_ws, size_t ws_size,
                              hipStream_t stream) {
  const float* x    = (const float*)d_in[0];
  const float* c1w  = (const float*)d_in[1];
  const float* c1b  = (const float*)d_in[2];
  const float* c2w  = (const float*)d_in[3];
  const float* c2b  = (const float*)d_in[4];
  const float* c3w  = (const float*)d_in[5];
  const float* c3b  = (const float*)d_in[6];
  const float* Wbn1 = (const float*)d_in[7];
  const float* gc1w = (const float*)d_in[8];
  const float* gc1b = (const float*)d_in[9];
  const float* Wbn2 = (const float*)d_in[10];
  const float* gc2w = (const float*)d_in[11];
  const float* gc2b = (const float*)d_in[12];
  const float* Wbn3 = (const float*)d_in[13];
  const float* gc3w = (const float*)d_in[14];
  const float* gc3b = (const float*)d_in[15];
  const float* clsw = (const float*)d_in[16];
  const float* clsb = (const float*)d_in[17];
  float* out = (float*)d_out;

  float* wsf = (float*)d_ws;
  float* H3  = wsf;                         // 31744*512 = 16,252,928 floats
  float* GP  = wsf + (size_t)16252928;      // 31744*96 = 3,047,424
  float* Hs1 = GP + (size_t)3047424;        // 512*62*64 = 2,031,616
  float* Hs2 = Hs1 + (size_t)2031616;       // total ~93 MB

  const int SOGC64_BYTES = 17508 * 4;       // 70,032 B dynamic LDS

  (void)hipFuncSetAttribute((const void*)sogc64_kernel<false>,
                            hipFuncAttributeMaxDynamicSharedMemorySize, SOGC64_BYTES);
  (void)hipFuncSetAttribute((const void*)sogc64_kernel<true>,
                            hipFuncAttributeMaxDynamicSharedMemorySize, SOGC64_BYTES);

  conv_chain_kernel<<<7936, 256, 0, stream>>>(x, c1w, c1b, c2w, c2b, c3w, c3b, H3);
  gp_kernel<<<992, 256, 0, stream>>>(H3, Wbn1, gc1w, GP);
  sogc1_kernel<<<512, 256, 0, stream>>>(GP, gc1b, Hs1);
  sogc64_kernel<false><<<512, 256, SOGC64_BYTES, stream>>>(
      Hs1, Wbn2, gc2w, gc2b, nullptr, nullptr, Hs2);
  sogc64_kernel<true><<<512, 256, SOGC64_BYTES, stream>>>(
      Hs2, Wbn3, gc3w, gc3b, clsw, clsb, out);
}